// Round 2
// baseline (380.369 us; speedup 1.0000x reference)
//
#include <hip/hip_runtime.h>
#include <hip/hip_bf16.h>
#include <math.h>

// ---------------------------------------------------------------------------
// MultiheadAttention: B=2, S=2048, D=1024, H=16, HD=64. ALL I/O is float32.
// Internal compute: fp16 MFMA (mfma_f32_16x16x32_f16) with fp32 accumulate.
//   1) qkv gemm (grid.z selects Q/K/V): X[4096,1024] @ W^T[1024,1024] + b
//      -> Q,K as fp16 [B,H,S,64]; V transposed fp16 [B,H,64,S]
//   2) flash attention (online softmax), out fp16 [B,S,1024] in ws
//   3) O projection (X fp16, W fp32) -> d_out float [B,S,1024]
// ---------------------------------------------------------------------------

typedef _Float16 h8 __attribute__((ext_vector_type(8)));
typedef float f4 __attribute__((ext_vector_type(4)));

#define MFMA16(a, b, c) __builtin_amdgcn_mfma_f32_16x16x32_f16((a), (b), (c), 0, 0, 0)

static constexpr int Bn = 2, Sn = 2048, Dn = 1024, Hn = 16, HDn = 64;
static constexpr int Mn = Bn * Sn;   // 4096 rows
static constexpr int Kn = Dn;        // 1024 reduction
static constexpr int Nn = Dn;        // 1024 cols
static constexpr int LDK = 72;       // padded LDS stride in halfs (64+8) -> 2-way alias (free)

__device__ __forceinline__ h8 cvt2(const float* p) {
  const float4 f0 = *(const float4*)p;
  const float4 f1 = *(const float4*)(p + 4);
  h8 h;
  h[0] = (_Float16)f0.x; h[1] = (_Float16)f0.y; h[2] = (_Float16)f0.z; h[3] = (_Float16)f0.w;
  h[4] = (_Float16)f1.x; h[5] = (_Float16)f1.y; h[6] = (_Float16)f1.z; h[7] = (_Float16)f1.w;
  return h;
}

struct GemmArgs {
  const void* X[3];          // float* (XF16=false) or _Float16* (XF16=true)
  const float* W[3];
  const float* bias[3];
  void* out[3];              // mode 0: float*, modes 1/2: _Float16*
  int mode[3];  // 0: plain [M,N] fp32; 1: fp16 [B,H,S,64]; 2: fp16 [B,H,64,S]
};

// C = X @ W^T + bias.  128x128 tile, 4 waves 2x2, each 64x64 (4x4 MFMA frags).
template <bool XF16>
__global__ __launch_bounds__(256) void gemm_bt(GemmArgs args) {
  const int z = blockIdx.z;
  const float* __restrict__ W = args.W[z];
  const float* __restrict__ bias = args.bias[z];
  const int mode = args.mode[z];

  __shared__ _Float16 As[128 * LDK];
  __shared__ _Float16 Bs[128 * LDK];

  const int t = threadIdx.x;
  const int lane = t & 63, wv = t >> 6;
  const int l15 = lane & 15, quad = lane >> 4;
  const int wm = (wv >> 1) * 64, wn = (wv & 1) * 64;
  const int n0 = blockIdx.x * 128, m0 = blockIdx.y * 128;

  f4 acc[4][4];
#pragma unroll
  for (int i = 0; i < 4; ++i)
#pragma unroll
    for (int j = 0; j < 4; ++j) {
      f4 zz = {0.f, 0.f, 0.f, 0.f};
      acc[i][j] = zz;
    }

  for (int k0 = 0; k0 < Kn; k0 += 64) {
    __syncthreads();
#pragma unroll
    for (int cc = 0; cc < 4; ++cc) {
      const int c = t + cc * 256;            // 1024 chunks of 8 elems per matrix
      const int row = c >> 3, c8 = c & 7;
      if (XF16) {
        const _Float16* Xh = (const _Float16*)args.X[z];
        *(uint4*)&As[row * LDK + c8 * 8] =
            *(const uint4*)(Xh + (size_t)(m0 + row) * Kn + k0 + c8 * 8);
      } else {
        const float* Xf = (const float*)args.X[z];
        *(h8*)&As[row * LDK + c8 * 8] =
            cvt2(Xf + (size_t)(m0 + row) * Kn + k0 + c8 * 8);
      }
      *(h8*)&Bs[row * LDK + c8 * 8] =
          cvt2(W + (size_t)(n0 + row) * Kn + k0 + c8 * 8);
    }
    __syncthreads();
#pragma unroll
    for (int kk = 0; kk < 64; kk += 32) {
      h8 af[4], bfr[4];
#pragma unroll
      for (int i = 0; i < 4; ++i)
        af[i] = *(const h8*)&As[(wm + i * 16 + l15) * LDK + kk + quad * 8];
#pragma unroll
      for (int j = 0; j < 4; ++j)
        bfr[j] = *(const h8*)&Bs[(wn + j * 16 + l15) * LDK + kk + quad * 8];
#pragma unroll
      for (int i = 0; i < 4; ++i)
#pragma unroll
        for (int j = 0; j < 4; ++j)
          acc[i][j] = MFMA16(af[i], bfr[j], acc[i][j]);
    }
  }

  // Epilogue: C/D layout col = lane&15, row = quad*4 + r  [m89/m91-verified]
#pragma unroll
  for (int j = 0; j < 4; ++j) {
    const int n = n0 + wn + j * 16 + l15;
    const float bv = bias[n];
#pragma unroll
    for (int i = 0; i < 4; ++i) {
      const int mb = m0 + wm + i * 16 + quad * 4;
#pragma unroll
      for (int r = 0; r < 4; ++r) {
        const int m = mb + r;
        const float fv = acc[i][j][r] + bv;
        if (mode == 0) {
          ((float*)args.out[z])[(size_t)m * Nn + n] = fv;
        } else {
          const int bb = m >> 11, ss = m & (Sn - 1);
          const int hh = n >> 6, hd = n & 63;
          _Float16* oh = (_Float16*)args.out[z];
          if (mode == 1)
            oh[(((size_t)(bb * Hn + hh)) * Sn + ss) * HDn + hd] = (_Float16)fv;
          else
            oh[(((size_t)(bb * Hn + hh)) * HDn + hd) * Sn + ss] = (_Float16)fv;
        }
      }
    }
  }
}

// Flash attention. Block = 256 = 4 waves; each wave owns 16 q rows.
// Grid: (S/64, B*H). K tile: 64 keys x 64 dims; V tile already [dim][key].
__global__ __launch_bounds__(256) void attn_kernel(
    const _Float16* __restrict__ Qh,   // [B,H,S,64]
    const _Float16* __restrict__ Kh,   // [B,H,S,64]
    const _Float16* __restrict__ Vt,   // [B,H,64,S]
    const float* __restrict__ mask,    // [B,S,S] fp32
    _Float16* __restrict__ out) {      // [B,S,1024] fp16
  __shared__ _Float16 Kl[64 * LDK];
  __shared__ _Float16 Vl[64 * LDK];
  __shared__ _Float16 Pl[4 * 16 * LDK];

  const int t = threadIdx.x;
  const int w = t >> 6, lane = t & 63;
  const int l15 = lane & 15, quad = lane >> 4;

  const int bh = blockIdx.y;
  const int b = bh >> 4, h = bh & 15;
  const size_t headoff = (size_t)bh * Sn * HDn;
  const _Float16* Qp = Qh + headoff;
  const _Float16* Kp = Kh + headoff;
  const _Float16* Vp = Vt + headoff;

  const int q0 = blockIdx.x * 64 + w * 16;  // this wave's first q row
  // A-operand frags: m = lane&15, k = quad*8+j; dims 0..31 and 32..63
  const h8 qf0 = *(const h8*)(Qp + (size_t)(q0 + l15) * HDn + quad * 8);
  const h8 qf1 = *(const h8*)(Qp + (size_t)(q0 + l15) * HDn + 32 + quad * 8);

  const float* mbase = mask + ((size_t)b * Sn + q0) * Sn;

  float m_r[4], l_r[4];
  f4 o_acc[4];
#pragma unroll
  for (int r = 0; r < 4; ++r) { m_r[r] = -INFINITY; l_r[r] = 0.f; }
#pragma unroll
  for (int nt = 0; nt < 4; ++nt) {
    f4 zz = {0.f, 0.f, 0.f, 0.f};
    o_acc[nt] = zz;
  }

  _Float16* Pw = &Pl[w * 16 * LDK];

  for (int kt = 0; kt < Sn / 64; ++kt) {
    __syncthreads();  // prior PV reads done before restage
#pragma unroll
    for (int cc = 0; cc < 2; ++cc) {
      const int c = t + cc * 256;  // 512 chunks of 8 halfs
      const int row = c >> 3, c8 = c & 7;
      *(uint4*)&Kl[row * LDK + c8 * 8] =
          *(const uint4*)(Kp + (size_t)(kt * 64 + row) * HDn + c8 * 8);
      *(uint4*)&Vl[row * LDK + c8 * 8] =
          *(const uint4*)(Vp + (size_t)row * Sn + kt * 64 + c8 * 8);
    }
    __syncthreads();

    // ---- QK^T for 4 subtiles of 16 keys, scaled + mask ----
    f4 s[4];
#pragma unroll
    for (int ks = 0; ks < 4; ++ks) {
      const h8 kf0 = *(const h8*)&Kl[(ks * 16 + l15) * LDK + quad * 8];
      const h8 kf1 = *(const h8*)&Kl[(ks * 16 + l15) * LDK + 32 + quad * 8];
      f4 a = {0.f, 0.f, 0.f, 0.f};
      a = MFMA16(qf0, kf0, a);
      a = MFMA16(qf1, kf1, a);
      const int kg = kt * 64 + ks * 16 + l15;
#pragma unroll
      for (int r = 0; r < 4; ++r)
        s[ks][r] = a[r] * 0.125f + mbase[(size_t)(quad * 4 + r) * Sn + kg];
    }

    // ---- online softmax over the 64-key tile ----
    float nm[4], alpha[4];
#pragma unroll
    for (int r = 0; r < 4; ++r) {
      float mx = fmaxf(fmaxf(s[0][r], s[1][r]), fmaxf(s[2][r], s[3][r]));
#pragma unroll
      for (int off = 1; off < 16; off <<= 1) mx = fmaxf(mx, __shfl_xor(mx, off));
      nm[r] = fmaxf(m_r[r], mx);
      alpha[r] = __expf(m_r[r] - nm[r]);
      m_r[r] = nm[r];
    }
#pragma unroll
    for (int ks = 0; ks < 4; ++ks)
#pragma unroll
      for (int r = 0; r < 4; ++r) s[ks][r] = __expf(s[ks][r] - nm[r]);
#pragma unroll
    for (int r = 0; r < 4; ++r) {
      float sm = s[0][r] + s[1][r] + s[2][r] + s[3][r];
#pragma unroll
      for (int off = 1; off < 16; off <<= 1) sm += __shfl_xor(sm, off);
      l_r[r] = l_r[r] * alpha[r] + sm;
    }
#pragma unroll
    for (int nt = 0; nt < 4; ++nt)
#pragma unroll
      for (int r = 0; r < 4; ++r) o_acc[nt][r] *= alpha[r];

    // ---- P (C-layout) -> LDS -> A-layout ----
#pragma unroll
    for (int ks = 0; ks < 4; ++ks)
#pragma unroll
      for (int r = 0; r < 4; ++r)
        Pw[(quad * 4 + r) * LDK + ks * 16 + l15] = (_Float16)s[ks][r];
    __syncthreads();

    // ---- PV: O[16 q x 64 d] += P[16 x 64keys] @ V[64keys x 64d] ----
#pragma unroll
    for (int kk = 0; kk < 64; kk += 32) {
      const h8 pf = *(const h8*)&Pw[l15 * LDK + kk + quad * 8];
#pragma unroll
      for (int nt = 0; nt < 4; ++nt) {
        const h8 vf = *(const h8*)&Vl[(nt * 16 + l15) * LDK + kk + quad * 8];
        o_acc[nt] = MFMA16(pf, vf, o_acc[nt]);
      }
    }
  }

  // epilogue: out[b, q, h*64 + d] = o/l  (fp16)
#pragma unroll
  for (int nt = 0; nt < 4; ++nt) {
#pragma unroll
    for (int r = 0; r < 4; ++r) {
      const int qg = q0 + quad * 4 + r;
      const int col = h * 64 + nt * 16 + l15;
      out[((size_t)b * Sn + qg) * Dn + col] = (_Float16)(o_acc[nt][r] / l_r[r]);
    }
  }
}

extern "C" void kernel_launch(void* const* d_in, const int* in_sizes, int n_in,
                              void* d_out, int out_size, void* d_ws, size_t ws_size,
                              hipStream_t stream) {
  const float* q = (const float*)d_in[0];
  const float* k = (const float*)d_in[1];
  const float* v = (const float*)d_in[2];
  const float* mask = (const float*)d_in[3];
  const float* WQ = (const float*)d_in[4];
  const float* bQ = (const float*)d_in[5];
  const float* WK = (const float*)d_in[6];
  const float* bK = (const float*)d_in[7];
  const float* WV = (const float*)d_in[8];
  const float* bV = (const float*)d_in[9];
  const float* WO = (const float*)d_in[10];
  const float* bO = (const float*)d_in[11];

  _Float16* ws = (_Float16*)d_ws;
  _Float16* Qh = ws;                       // [B,H,S,64]  fp16 8 MB
  _Float16* Kh = ws + (size_t)4194304;     // [B,H,S,64]  fp16 8 MB
  _Float16* Vt = ws + (size_t)8388608;     // [B,H,64,S]  fp16 8 MB
  _Float16* AO = ws + (size_t)12582912;    // [B,S,1024]  fp16 8 MB

  GemmArgs ga;
  ga.X[0] = q;  ga.W[0] = WQ; ga.bias[0] = bQ; ga.out[0] = Qh; ga.mode[0] = 1;
  ga.X[1] = k;  ga.W[1] = WK; ga.bias[1] = bK; ga.out[1] = Kh; ga.mode[1] = 1;
  ga.X[2] = v;  ga.W[2] = WV; ga.bias[2] = bV; ga.out[2] = Vt; ga.mode[2] = 2;
  gemm_bt<false><<<dim3(Nn / 128, Mn / 128, 3), 256, 0, stream>>>(ga);

  attn_kernel<<<dim3(Sn / 64, Bn * Hn), 256, 0, stream>>>(Qh, Kh, Vt, mask, AO);

  GemmArgs go;
  for (int i = 0; i < 3; ++i) {
    go.X[i] = AO; go.W[i] = WO; go.bias[i] = bO;
    go.out[i] = d_out; go.mode[i] = 0;
  }
  gemm_bt<true><<<dim3(Nn / 128, Mn / 128, 1), 256, 0, stream>>>(go);
}